// Round 4
// baseline (638.899 us; speedup 1.0000x reference)
//
#include <hip/hip_runtime.h>
#include <hip/hip_bf16.h>

#define NPTS 8192
#define DIM  512
#define NHEAD 8
#define HDIM 64

typedef short bf16x8 __attribute__((ext_vector_type(8)));   // 8 bf16 = 4 VGPRs
typedef float f32x4  __attribute__((ext_vector_type(4)));   // MFMA C/D

#if __has_builtin(__builtin_amdgcn_exp2f)
#define EXP2F(x) __builtin_amdgcn_exp2f(x)
#else
#define EXP2F(x) __expf((x) * 0.6931471805599453f)
#endif

// fp32 -> bf16 round-nearest-even
__device__ __forceinline__ unsigned short f2bf(float f) {
    union { float f; unsigned int u; } v; v.f = f;
    unsigned int r = v.u + 0x7FFFu + ((v.u >> 16) & 1u);
    return (unsigned short)(r >> 16);
}

// ---------------------------------------------------------------------------
// Prep 1: x fp32 -> bf16 (8 elems/thread)
// ---------------------------------------------------------------------------
__global__ __launch_bounds__(256) void cvt_x_kernel(
    const float* __restrict__ in, unsigned short* __restrict__ outp)
{
    int gid = blockIdx.x * 256 + threadIdx.x;   // over N*DIM/8
    float4 a = ((const float4*)in)[gid * 2];
    float4 b = ((const float4*)in)[gid * 2 + 1];
    ushort4 ua, ub;
    ua.x = f2bf(a.x); ua.y = f2bf(a.y); ua.z = f2bf(a.z); ua.w = f2bf(a.w);
    ub.x = f2bf(b.x); ub.y = f2bf(b.y); ub.z = f2bf(b.z); ub.w = f2bf(b.w);
    ((ushort4*)outp)[gid * 2]     = ua;
    ((ushort4*)outp)[gid * 2 + 1] = ub;
}

// ---------------------------------------------------------------------------
// Prep 2: Wq/Wk/Wv [h][512][64] fp32 -> wtq [zh][64][512] bf16 (transposed)
// ---------------------------------------------------------------------------
__global__ __launch_bounds__(256) void tr_w_kernel(
    const float* __restrict__ Wq, const float* __restrict__ Wk,
    const float* __restrict__ Wv, unsigned short* __restrict__ wtq)
{
    int zh = blockIdx.z, z = zh >> 3, h = zh & 7;
    const float* src = (z == 0 ? Wq : z == 1 ? Wk : Wv) + (size_t)h * DIM * HDIM;
    unsigned short* dst = wtq + (size_t)zh * HDIM * DIM;
    int k0 = blockIdx.x * 64;
    __shared__ float tile[64][65];
    int t = threadIdx.x, c = t & 63, r = t >> 6;
    #pragma unroll
    for (int i = 0; i < 16; ++i)
        tile[r + 4 * i][c] = src[(size_t)(k0 + r + 4 * i) * HDIM + c];
    __syncthreads();
    #pragma unroll
    for (int i = 0; i < 16; ++i)
        dst[(size_t)(r + 4 * i) * DIM + k0 + c] = f2bf(tile[c][r + 4 * i]);
}

// ---------------------------------------------------------------------------
// Prep 3: Wo [512][512] fp32 -> wot [512][512] bf16 transposed ([e_out][k])
// ---------------------------------------------------------------------------
__global__ __launch_bounds__(256) void tr_wo_kernel(
    const float* __restrict__ Wo, unsigned short* __restrict__ wot)
{
    int k0 = blockIdx.x * 64, e0 = blockIdx.y * 64;
    __shared__ float tile[64][65];
    int t = threadIdx.x, c = t & 63, r = t >> 6;
    #pragma unroll
    for (int i = 0; i < 16; ++i)
        tile[r + 4 * i][c] = Wo[(size_t)(k0 + r + 4 * i) * DIM + e0 + c];
    __syncthreads();
    #pragma unroll
    for (int i = 0; i < 16; ++i)
        wot[(size_t)(e0 + r + 4 * i) * DIM + k0 + c] = f2bf(tile[c][r + 4 * i]);
}

// ---------------------------------------------------------------------------
// QKV projection, bf16 MFMA, no LDS / no barriers. Block 4 waves, each wave
// 32 rows x 64 cols, K=512. A/B frags direct from global (L2-resident).
//   z=0: q_bf[h][n][e]  (scale*log2e folded)   z=1: k_bf[h][n][e]
//   z=2: vt_bf[h][e][kappa(n)]  kappa = (n&~63)+4*(n&15)+((n>>4)&3)
// ---------------------------------------------------------------------------
__global__ __launch_bounds__(256) void qkv_mfma_kernel(
    const unsigned short* __restrict__ xbf,   // [N][512] bf16
    const unsigned short* __restrict__ wtq,   // [24][64][512] bf16
    const float* __restrict__ bq, const float* __restrict__ bk,
    const float* __restrict__ bv,
    unsigned short* __restrict__ q_bf, unsigned short* __restrict__ k_bf,
    unsigned short* __restrict__ vt_bf)
{
    const int zh = blockIdx.y, z = zh >> 3, h = zh & 7;
    const unsigned short* W = wtq + (size_t)zh * HDIM * DIM;
    const float* b = (z == 0 ? bq : z == 1 ? bk : bv) + h * HDIM;
    const int t = threadIdx.x, w = t >> 6, lane = t & 63;
    const int l15 = lane & 15, quad = lane >> 4;
    const int r0 = blockIdx.x * 128 + w * 32;

    f32x4 O[2][4];
    #pragma unroll
    for (int mt = 0; mt < 2; ++mt)
        #pragma unroll
        for (int tn = 0; tn < 4; ++tn) O[mt][tn] = (f32x4){0.f, 0.f, 0.f, 0.f};

    for (int k0 = 0; k0 < DIM; k0 += 64) {
        bf16x8 af[2][2], bf[4][2];
        #pragma unroll
        for (int mt = 0; mt < 2; ++mt)
            #pragma unroll
            for (int kc = 0; kc < 2; ++kc)
                af[mt][kc] = *(const bf16x8*)
                    &xbf[(size_t)(r0 + 16 * mt + l15) * DIM + k0 + quad * 8 + 32 * kc];
        #pragma unroll
        for (int tn = 0; tn < 4; ++tn)
            #pragma unroll
            for (int kc = 0; kc < 2; ++kc)
                bf[tn][kc] = *(const bf16x8*)
                    &W[(size_t)(l15 + 16 * tn) * DIM + k0 + quad * 8 + 32 * kc];
        #pragma unroll
        for (int mt = 0; mt < 2; ++mt)
            #pragma unroll
            for (int tn = 0; tn < 4; ++tn) {
                O[mt][tn] = __builtin_amdgcn_mfma_f32_16x16x32_bf16(
                    af[mt][0], bf[tn][0], O[mt][tn], 0, 0, 0);
                O[mt][tn] = __builtin_amdgcn_mfma_f32_16x16x32_bf16(
                    af[mt][1], bf[tn][1], O[mt][tn], 0, 0, 0);
            }
    }

    if (z < 2) {
        unsigned short* outp = (z == 0 ? q_bf : k_bf) + (size_t)h * NPTS * HDIM;
        const float sc = (z == 0) ? 0.18033688011112042f : 1.0f;  // 0.125*log2e | 1
        #pragma unroll
        for (int mt = 0; mt < 2; ++mt)
            #pragma unroll
            for (int tn = 0; tn < 4; ++tn) {
                int e = l15 + 16 * tn;
                float be = b[e];
                #pragma unroll
                for (int r = 0; r < 4; ++r) {
                    int n = r0 + 16 * mt + quad * 4 + r;
                    outp[(size_t)n * HDIM + e] = f2bf((O[mt][tn][r] + be) * sc);
                }
            }
    } else {
        unsigned short* vt = vt_bf + (size_t)h * HDIM * NPTS;
        #pragma unroll
        for (int mt = 0; mt < 2; ++mt)
            #pragma unroll
            for (int tn = 0; tn < 4; ++tn) {
                int e = l15 + 16 * tn;
                float be = b[e];
                #pragma unroll
                for (int r = 0; r < 4; ++r) {
                    int n = r0 + 16 * mt + quad * 4 + r;
                    int kap = (n & ~63) + ((n & 15) << 2) + ((n >> 4) & 3);
                    vt[(size_t)e * NPTS + kap] = f2bf(O[mt][tn][r] + be);
                }
            }
    }
}

// ---------------------------------------------------------------------------
// Barrier-free MFMA flash attention (max-free softmax, full 8192 keys).
// Block = 4 waves x 32 qrows = 128 qrows. K frags double-buffered in regs
// (prefetch 1 tile ahead, direct global); V frags issued at iter-top, used
// after softmax; P round-trips a wave-private LDS strip (lgkmcnt only).
// Writes normalized bf16 heads output op[n][h*64+e].
// ---------------------------------------------------------------------------
__global__ __launch_bounds__(256, 2) void attn_kernel(
    const unsigned short* __restrict__ qg,   // [H][N][64] bf16, pre-scaled
    const unsigned short* __restrict__ kg,   // [H][N][64] bf16
    const unsigned short* __restrict__ vtg,  // [H][64][N] bf16, kappa-permuted
    unsigned short* __restrict__ op)         // [N][512] bf16 normalized
{
    const int h  = blockIdx.y;
    const int q0 = blockIdx.x * 128;
    const unsigned short* Q  = qg  + (size_t)h * NPTS * HDIM;
    const unsigned short* K  = kg  + (size_t)h * NPTS * HDIM;
    const unsigned short* Vt = vtg + (size_t)h * HDIM * NPTS;

    __shared__ __align__(16) unsigned short Plds[128 * 64];   // 16 KB, wave-private strips

    const int t    = threadIdx.x;
    const int w    = t >> 6;
    const int lane = t & 63;
    const int l15  = lane & 15;
    const int quad = lane >> 4;

    const int koff0 = l15 * 64 + (quad ^ (l15 & 7)) * 8;   // P A-frag read offs
    const int koff1 = koff0 ^ 32;

    // Q A-frags (constant over loop)
    bf16x8 qf[2][2];
    #pragma unroll
    for (int mt = 0; mt < 2; ++mt)
        #pragma unroll
        for (int kc = 0; kc < 2; ++kc)
            qf[mt][kc] = *(const bf16x8*)
                &Q[(size_t)(q0 + 32 * w + 16 * mt + l15) * HDIM + quad * 8 + 32 * kc];

    f32x4 O[2][4];
    float lsum[2][4];
    #pragma unroll
    for (int mt = 0; mt < 2; ++mt) {
        #pragma unroll
        for (int tn = 0; tn < 4; ++tn) O[mt][tn] = (f32x4){0.f, 0.f, 0.f, 0.f};
        #pragma unroll
        for (int r = 0; r < 4; ++r) lsum[mt][r] = 0.f;
    }

    bf16x8 kfA[4][2], kfB[4][2];

    auto loadK = [&](bf16x8 (&kf)[4][2], int kt) {
        #pragma unroll
        for (int tn = 0; tn < 4; ++tn)
            #pragma unroll
            for (int kc = 0; kc < 2; ++kc)
                kf[tn][kc] = *(const bf16x8*)
                    &K[(size_t)(kt + 16 * tn + l15) * HDIM + quad * 8 + 32 * kc];
    };

    auto body = [&](int kt, bf16x8 (&kf)[4][2]) {
        // V frags for this tile (consumed after softmax -> latency covered)
        bf16x8 vf[4][2];
        #pragma unroll
        for (int tn = 0; tn < 4; ++tn)
            #pragma unroll
            for (int kc = 0; kc < 2; ++kc)
                vf[tn][kc] = *(const bf16x8*)
                    &Vt[(size_t)(16 * tn + l15) * NPTS + kt + quad * 8 + 32 * kc];

        // S = Q K^T
        f32x4 S[2][4];
        #pragma unroll
        for (int mt = 0; mt < 2; ++mt)
            #pragma unroll
            for (int tn = 0; tn < 4; ++tn) S[mt][tn] = (f32x4){0.f, 0.f, 0.f, 0.f};
        #pragma unroll
        for (int mt = 0; mt < 2; ++mt)
            #pragma unroll
            for (int tn = 0; tn < 4; ++tn) {
                S[mt][tn] = __builtin_amdgcn_mfma_f32_16x16x32_bf16(
                    qf[mt][0], kf[tn][0], S[mt][tn], 0, 0, 0);
                S[mt][tn] = __builtin_amdgcn_mfma_f32_16x16x32_bf16(
                    qf[mt][1], kf[tn][1], S[mt][tn], 0, 0, 0);
            }

        // max-free softmax: P = exp2(S); packed P -> wave-private LDS strip
        #pragma unroll
        for (int mt = 0; mt < 2; ++mt)
            #pragma unroll
            for (int r = 0; r < 4; ++r) {
                float e0 = EXP2F(S[mt][0][r]);
                float e1 = EXP2F(S[mt][1][r]);
                float e2 = EXP2F(S[mt][2][r]);
                float e3 = EXP2F(S[mt][3][r]);
                lsum[mt][r] += (e0 + e1) + (e2 + e3);
                uint2 pk;
                pk.x = (unsigned int)f2bf(e0) | ((unsigned int)f2bf(e1) << 16);
                pk.y = (unsigned int)f2bf(e2) | ((unsigned int)f2bf(e3) << 16);
                int row = 32 * w + 16 * mt + quad * 4 + r;
                *(uint2*)&Plds[row * 64 + (((l15 >> 1) ^ (row & 7)) << 3)
                               + ((l15 & 1) << 2)] = pk;
            }

        // O += P V (wave-private strip: lgkmcnt dependency only, no barrier)
        bf16x8 pf[2][2];
        #pragma unroll
        for (int mt = 0; mt < 2; ++mt) {
            pf[mt][0] = *(const bf16x8*)&Plds[(32 * w + 16 * mt) * 64 + koff0];
            pf[mt][1] = *(const bf16x8*)&Plds[(32 * w + 16 * mt) * 64 + koff1];
        }
        #pragma unroll
        for (int mt = 0; mt < 2; ++mt)
            #pragma unroll
            for (int tn = 0; tn < 4; ++tn) {
                O[mt][tn] = __builtin_amdgcn_mfma_f32_16x16x32_bf16(
                    pf[mt][0], vf[tn][0], O[mt][tn], 0, 0, 0);
                O[mt][tn] = __builtin_amdgcn_mfma_f32_16x16x32_bf16(
                    pf[mt][1], vf[tn][1], O[mt][tn], 0, 0, 0);
            }
    };

    loadK(kfA, 0);
    for (int kt = 0; kt < NPTS; kt += 128) {
        loadK(kfB, kt + 64);
        body(kt, kfA);
        loadK(kfA, (kt + 128 < NPTS) ? kt + 128 : kt + 64);  // last: harmless reload
        body(kt + 64, kfB);
    }

    // epilogue: reduce l over the 16 col-lanes, normalize, store bf16
    #pragma unroll
    for (int mt = 0; mt < 2; ++mt)
        #pragma unroll
        for (int r = 0; r < 4; ++r) {
            float l = lsum[mt][r];
            l += __shfl_xor(l, 1);
            l += __shfl_xor(l, 2);
            l += __shfl_xor(l, 4);
            l += __shfl_xor(l, 8);
            float inv = 1.0f / l;
            int n = q0 + 32 * w + 16 * mt + quad * 4 + r;
            #pragma unroll
            for (int tn = 0; tn < 4; ++tn)
                op[(size_t)n * DIM + h * HDIM + l15 + 16 * tn] =
                    f2bf(O[mt][tn][r] * inv);
        }
}

// ---------------------------------------------------------------------------
// Output projection, bf16 MFMA, no LDS / no barriers. out = cc@Wo + bo + x.
// Block 4 waves, each 32 rows x 64 cols; K=512; frags direct from global.
// ---------------------------------------------------------------------------
__global__ __launch_bounds__(256) void out_mfma_kernel(
    const unsigned short* __restrict__ cc,    // [N][512] bf16 normalized heads
    const unsigned short* __restrict__ wot,   // [512][512] bf16 [e_out][k]
    const float* __restrict__ bo, const float* __restrict__ x,
    float* __restrict__ outp)
{
    const int t = threadIdx.x, w = t >> 6, lane = t & 63;
    const int l15 = lane & 15, quad = lane >> 4;
    const int r0 = blockIdx.x * 128 + w * 32;
    const int c0 = blockIdx.y * 64;

    f32x4 O[2][4];
    #pragma unroll
    for (int mt = 0; mt < 2; ++mt)
        #pragma unroll
        for (int tn = 0; tn < 4; ++tn) O[mt][tn] = (f32x4){0.f, 0.f, 0.f, 0.f};

    for (int k0 = 0; k0 < DIM; k0 += 64) {
        bf16x8 af[2][2], bf[4][2];
        #pragma unroll
        for (int mt = 0; mt < 2; ++mt)
            #pragma unroll
            for (int kc = 0; kc < 2; ++kc)
                af[mt][kc] = *(const bf16x8*)
                    &cc[(size_t)(r0 + 16 * mt + l15) * DIM + k0 + quad * 8 + 32 * kc];
        #pragma unroll
        for (int tn = 0; tn < 4; ++tn)
            #pragma unroll
            for (int kc = 0; kc < 2; ++kc)
                bf[tn][kc] = *(const bf16x8*)
                    &wot[(size_t)(c0 + l15 + 16 * tn) * DIM + k0 + quad * 8 + 32 * kc];
        #pragma unroll
        for (int mt = 0; mt < 2; ++mt)
            #pragma unroll
            for (int tn = 0; tn < 4; ++tn) {
                O[mt][tn] = __builtin_amdgcn_mfma_f32_16x16x32_bf16(
                    af[mt][0], bf[tn][0], O[mt][tn], 0, 0, 0);
                O[mt][tn] = __builtin_amdgcn_mfma_f32_16x16x32_bf16(
                    af[mt][1], bf[tn][1], O[mt][tn], 0, 0, 0);
            }
    }

    #pragma unroll
    for (int mt = 0; mt < 2; ++mt)
        #pragma unroll
        for (int tn = 0; tn < 4; ++tn) {
            int e = c0 + l15 + 16 * tn;
            float be = bo[e];
            #pragma unroll
            for (int r = 0; r < 4; ++r) {
                int n = r0 + 16 * mt + quad * 4 + r;
                outp[(size_t)n * DIM + e] = O[mt][tn][r] + be + x[(size_t)n * DIM + e];
            }
        }
}

extern "C" void kernel_launch(void* const* d_in, const int* in_sizes, int n_in,
                              void* d_out, int out_size, void* d_ws, size_t ws_size,
                              hipStream_t stream) {
    const float* x  = (const float*)d_in[0];
    const float* Wq = (const float*)d_in[1];
    const float* bq = (const float*)d_in[2];
    const float* Wk = (const float*)d_in[3];
    const float* bk = (const float*)d_in[4];
    const float* Wv = (const float*)d_in[5];
    const float* bv = (const float*)d_in[6];
    const float* Wo = (const float*)d_in[7];
    const float* bo = (const float*)d_in[8];
    float* out = (float*)d_out;

    const size_t per = (size_t)NHEAD * NPTS * HDIM;            // 4M elems
    unsigned short* xbf   = (unsigned short*)d_ws;             //  8 MB
    unsigned short* wtq   = xbf + (size_t)NPTS * DIM;          //  1.5 MB
    unsigned short* wot   = wtq + (size_t)24 * HDIM * DIM;     //  0.5 MB
    unsigned short* q_bf  = wot + (size_t)DIM * DIM;           //  8 MB
    unsigned short* k_bf  = q_bf + per;                        //  8 MB
    unsigned short* vt_bf = k_bf + per;                        //  8 MB
    unsigned short* op    = vt_bf + per;                       //  8 MB
    // total ws: 42 MB

    cvt_x_kernel<<<dim3(NPTS * DIM / 8 / 256), 256, 0, stream>>>(x, xbf);
    tr_w_kernel<<<dim3(8, 1, 24), 256, 0, stream>>>(Wq, Wk, Wv, wtq);
    tr_wo_kernel<<<dim3(8, 8), 256, 0, stream>>>(Wo, wot);
    qkv_mfma_kernel<<<dim3(NPTS / 128, 24), 256, 0, stream>>>(
        xbf, wtq, bq, bk, bv, q_bf, k_bf, vt_bf);
    attn_kernel<<<dim3(NPTS / 128, NHEAD), 256, 0, stream>>>(
        q_bf, k_bf, vt_bf, op);
    out_mfma_kernel<<<dim3(NPTS / 128, DIM / 64), 256, 0, stream>>>(
        op, wot, bo, x, out);
}

// Round 5
// 562.864 us; speedup vs baseline: 1.1351x; 1.1351x over previous
//
#include <hip/hip_runtime.h>
#include <hip/hip_bf16.h>

#define NPTS 8192
#define DIM  512
#define NHEAD 8
#define HDIM 64

typedef short bf16x8 __attribute__((ext_vector_type(8)));   // 8 bf16 = 4 VGPRs
typedef float f32x4  __attribute__((ext_vector_type(4)));   // MFMA C/D

#define GLOBAL_AS __attribute__((address_space(1)))
#define LDS_AS    __attribute__((address_space(3)))

#if __has_builtin(__builtin_amdgcn_exp2f)
#define EXP2F(x) __builtin_amdgcn_exp2f(x)
#else
#define EXP2F(x) __expf((x) * 0.6931471805599453f)
#endif

// fp32 -> bf16 round-nearest-even
__device__ __forceinline__ unsigned short f2bf(float f) {
    union { float f; unsigned int u; } v; v.f = f;
    unsigned int r = v.u + 0x7FFFu + ((v.u >> 16) & 1u);
    return (unsigned short)(r >> 16);
}
__device__ __forceinline__ float bf2f(unsigned short u) {
    union { unsigned int i; float f; } v; v.i = ((unsigned int)u) << 16;
    return v.f;
}

// ---------------------------------------------------------------------------
// Prep 1: x fp32 -> bf16
// ---------------------------------------------------------------------------
__global__ __launch_bounds__(256) void cvt_x_kernel(
    const float* __restrict__ in, unsigned short* __restrict__ outp)
{
    int gid = blockIdx.x * 256 + threadIdx.x;   // over N*DIM/8
    float4 a = ((const float4*)in)[gid * 2];
    float4 b = ((const float4*)in)[gid * 2 + 1];
    ushort4 ua, ub;
    ua.x = f2bf(a.x); ua.y = f2bf(a.y); ua.z = f2bf(a.z); ua.w = f2bf(a.w);
    ub.x = f2bf(b.x); ub.y = f2bf(b.y); ub.z = f2bf(b.z); ub.w = f2bf(b.w);
    ((ushort4*)outp)[gid * 2]     = ua;
    ((ushort4*)outp)[gid * 2 + 1] = ub;
}

// ---------------------------------------------------------------------------
// Prep 2: Wq/Wk/Wv [h][512][64] fp32 -> wtq [zh][64][512] bf16 (transposed)
// ---------------------------------------------------------------------------
__global__ __launch_bounds__(256) void tr_w_kernel(
    const float* __restrict__ Wq, const float* __restrict__ Wk,
    const float* __restrict__ Wv, unsigned short* __restrict__ wtq)
{
    int zh = blockIdx.z, z = zh >> 3, h = zh & 7;
    const float* src = (z == 0 ? Wq : z == 1 ? Wk : Wv) + (size_t)h * DIM * HDIM;
    unsigned short* dst = wtq + (size_t)zh * HDIM * DIM;
    int k0 = blockIdx.x * 64;
    __shared__ float tile[64][65];
    int t = threadIdx.x, c = t & 63, r = t >> 6;
    #pragma unroll
    for (int i = 0; i < 16; ++i)
        tile[r + 4 * i][c] = src[(size_t)(k0 + r + 4 * i) * HDIM + c];
    __syncthreads();
    #pragma unroll
    for (int i = 0; i < 16; ++i)
        dst[(size_t)(r + 4 * i) * DIM + k0 + c] = f2bf(tile[c][r + 4 * i]);
}

// ---------------------------------------------------------------------------
// Prep 3: Wo [512][512] fp32 -> wot [512][512] bf16 transposed ([e_out][k])
// ---------------------------------------------------------------------------
__global__ __launch_bounds__(256) void tr_wo_kernel(
    const float* __restrict__ Wo, unsigned short* __restrict__ wot)
{
    int k0 = blockIdx.x * 64, e0 = blockIdx.y * 64;
    __shared__ float tile[64][65];
    int t = threadIdx.x, c = t & 63, r = t >> 6;
    #pragma unroll
    for (int i = 0; i < 16; ++i)
        tile[r + 4 * i][c] = Wo[(size_t)(k0 + r + 4 * i) * DIM + e0 + c];
    __syncthreads();
    #pragma unroll
    for (int i = 0; i < 16; ++i)
        wot[(size_t)(e0 + r + 4 * i) * DIM + k0 + c] = f2bf(tile[c][r + 4 * i]);
}

// ---------------------------------------------------------------------------
// QKV projection, bf16 MFMA, direct-global frags (R4, kept).
//   z=0: q_bf[h][n][e]  (scale*log2e folded)   z=1: k_bf[h][n][e]
//   z=2: vt_bf[h][e][kappa(n)]  kappa = (n&~63)+4*(n&15)+((n>>4)&3)
// ---------------------------------------------------------------------------
__global__ __launch_bounds__(256) void qkv_mfma_kernel(
    const unsigned short* __restrict__ xbf,   // [N][512] bf16
    const unsigned short* __restrict__ wtq,   // [24][64][512] bf16
    const float* __restrict__ bq, const float* __restrict__ bk,
    const float* __restrict__ bv,
    unsigned short* __restrict__ q_bf, unsigned short* __restrict__ k_bf,
    unsigned short* __restrict__ vt_bf)
{
    const int zh = blockIdx.y, z = zh >> 3, h = zh & 7;
    const unsigned short* W = wtq + (size_t)zh * HDIM * DIM;
    const float* b = (z == 0 ? bq : z == 1 ? bk : bv) + h * HDIM;
    const int t = threadIdx.x, w = t >> 6, lane = t & 63;
    const int l15 = lane & 15, quad = lane >> 4;
    const int r0 = blockIdx.x * 128 + w * 32;

    f32x4 O[2][4];
    #pragma unroll
    for (int mt = 0; mt < 2; ++mt)
        #pragma unroll
        for (int tn = 0; tn < 4; ++tn) O[mt][tn] = (f32x4){0.f, 0.f, 0.f, 0.f};

    for (int k0 = 0; k0 < DIM; k0 += 64) {
        bf16x8 af[2][2], bf[4][2];
        #pragma unroll
        for (int mt = 0; mt < 2; ++mt)
            #pragma unroll
            for (int kc = 0; kc < 2; ++kc)
                af[mt][kc] = *(const bf16x8*)
                    &xbf[(size_t)(r0 + 16 * mt + l15) * DIM + k0 + quad * 8 + 32 * kc];
        #pragma unroll
        for (int tn = 0; tn < 4; ++tn)
            #pragma unroll
            for (int kc = 0; kc < 2; ++kc)
                bf[tn][kc] = *(const bf16x8*)
                    &W[(size_t)(l15 + 16 * tn) * DIM + k0 + quad * 8 + 32 * kc];
        #pragma unroll
        for (int mt = 0; mt < 2; ++mt)
            #pragma unroll
            for (int tn = 0; tn < 4; ++tn) {
                O[mt][tn] = __builtin_amdgcn_mfma_f32_16x16x32_bf16(
                    af[mt][0], bf[tn][0], O[mt][tn], 0, 0, 0);
                O[mt][tn] = __builtin_amdgcn_mfma_f32_16x16x32_bf16(
                    af[mt][1], bf[tn][1], O[mt][tn], 0, 0, 0);
            }
    }

    if (z < 2) {
        unsigned short* outp = (z == 0 ? q_bf : k_bf) + (size_t)h * NPTS * HDIM;
        const float sc = (z == 0) ? 0.18033688011112042f : 1.0f;  // 0.125*log2e | 1
        #pragma unroll
        for (int mt = 0; mt < 2; ++mt)
            #pragma unroll
            for (int tn = 0; tn < 4; ++tn) {
                int e = l15 + 16 * tn;
                float be = b[e];
                #pragma unroll
                for (int r = 0; r < 4; ++r) {
                    int n = r0 + 16 * mt + quad * 4 + r;
                    outp[(size_t)n * HDIM + e] = f2bf((O[mt][tn][r] + be) * sc);
                }
            }
    } else {
        unsigned short* vt = vt_bf + (size_t)h * HDIM * NPTS;
        #pragma unroll
        for (int mt = 0; mt < 2; ++mt)
            #pragma unroll
            for (int tn = 0; tn < 4; ++tn) {
                int e = l15 + 16 * tn;
                float be = b[e];
                #pragma unroll
                for (int r = 0; r < 4; ++r) {
                    int n = r0 + 16 * mt + quad * 4 + r;
                    int kap = (n & ~63) + ((n & 15) << 2) + ((n >> 4) & 3);
                    vt[(size_t)e * NPTS + kap] = f2bf(O[mt][tn][r] + be);
                }
            }
    }
}

// ---------------------------------------------------------------------------
// MFMA flash attention, R5: R3 structure + double-buffered K staging (one
// barrier/iter, stage issued a full body ahead) + 4-wave blocks (128 qrows).
// K via global_load_lds w=16 + XOR source swizzle; V frags direct from
// kappa-ordered global; P via wave-private LDS strip; max-free softmax;
// k-split 2 with linear partials merged by reduce_kernel.
// ---------------------------------------------------------------------------
__global__ __launch_bounds__(256, 4) void attn_kernel(
    const unsigned short* __restrict__ qg,   // [H][N][64] bf16, pre-scaled
    const unsigned short* __restrict__ kg,   // [H][N][64] bf16
    const unsigned short* __restrict__ vtg,  // [H][64][N] bf16, kappa-permuted
    unsigned short* __restrict__ opart,      // [2][N][DIM] bf16 unnormalized
    float* __restrict__ lpart)               // [2][H][N] fp32
{
    const int h  = blockIdx.y;
    const int ks = blockIdx.z;
    const int q0 = blockIdx.x * 128;
    const int kbase = ks * (NPTS / 2);
    const unsigned short* Q  = qg  + (size_t)h * NPTS * HDIM;
    const unsigned short* K  = kg  + (size_t)h * NPTS * HDIM;
    const unsigned short* Vt = vtg + (size_t)h * HDIM * NPTS;
    unsigned short* op = opart + (size_t)ks * NPTS * DIM;
    float* lp = lpart + (size_t)(ks * NHEAD + h) * NPTS;

    __shared__ __align__(16) unsigned short Klds[2][64 * 64];  // 2 x 8 KB
    __shared__ __align__(16) unsigned short Plds[128 * 64];    // 16 KB

    const int t    = threadIdx.x;
    const int w    = t >> 6;
    const int lane = t & 63;
    const int l15  = lane & 15;
    const int quad = lane >> 4;

    const int koff0 = l15 * 64 + (quad ^ (l15 & 7)) * 8;
    const int koff1 = koff0 ^ 32;

    const int srow   = lane >> 3;
    const int schunk = (lane & 7) ^ srow;

    // Q A-frags: rows q0 + 32w + 16mt + l15
    bf16x8 qf[2][2];
    #pragma unroll
    for (int mt = 0; mt < 2; ++mt)
        #pragma unroll
        for (int kc = 0; kc < 2; ++kc)
            qf[mt][kc] = *(const bf16x8*)
                &Q[(size_t)(q0 + 32 * w + 16 * mt + l15) * HDIM + quad * 8 + 32 * kc];

    f32x4 O[2][4];
    float lsum[2][4];
    #pragma unroll
    for (int mt = 0; mt < 2; ++mt) {
        #pragma unroll
        for (int tn = 0; tn < 4; ++tn) O[mt][tn] = (f32x4){0.f, 0.f, 0.f, 0.f};
        #pragma unroll
        for (int r = 0; r < 4; ++r) lsum[mt][r] = 0.f;
    }

    // stage one 64-key tile into Klds[buf]; 4 waves x 2 issues x 16B/lane
    auto stage = [&](int kt, int buf) {
        #pragma unroll
        for (int i = 0; i < 2; ++i) {
            int rb = 16 * w + 8 * i;
            __builtin_amdgcn_global_load_lds(
                (const GLOBAL_AS void*)&K[(size_t)(kbase + kt + rb + srow) * HDIM
                                          + schunk * 8],
                (LDS_AS void*)&Klds[buf][rb * 64], 16, 0, 0);
        }
    };

    stage(0, 0);
    __syncthreads();
    int buf = 0;

    for (int kt = 0; kt < NPTS / 2; kt += 64) {
        // issue next stage first: latency hidden behind this body's compute
        if (kt + 64 < NPTS / 2) stage(kt + 64, buf ^ 1);

        // V frags for this tile (global, consumed after softmax)
        bf16x8 vf[4][2];
        #pragma unroll
        for (int tn = 0; tn < 4; ++tn)
            #pragma unroll
            for (int kc = 0; kc < 2; ++kc)
                vf[tn][kc] = *(const bf16x8*)
                    &Vt[(size_t)(16 * tn + l15) * NPTS + kbase + kt + quad * 8 + 32 * kc];

        // K frags from LDS
        bf16x8 kf[4][2];
        #pragma unroll
        for (int tn = 0; tn < 4; ++tn) {
            kf[tn][0] = *(const bf16x8*)&Klds[buf][1024 * tn + koff0];
            kf[tn][1] = *(const bf16x8*)&Klds[buf][1024 * tn + koff1];
        }

        // S = Q K^T
        f32x4 S[2][4];
        #pragma unroll
        for (int mt = 0; mt < 2; ++mt)
            #pragma unroll
            for (int tn = 0; tn < 4; ++tn) S[mt][tn] = (f32x4){0.f, 0.f, 0.f, 0.f};
        #pragma unroll
        for (int mt = 0; mt < 2; ++mt)
            #pragma unroll
            for (int tn = 0; tn < 4; ++tn) {
                S[mt][tn] = __builtin_amdgcn_mfma_f32_16x16x32_bf16(
                    qf[mt][0], kf[tn][0], S[mt][tn], 0, 0, 0);
                S[mt][tn] = __builtin_amdgcn_mfma_f32_16x16x32_bf16(
                    qf[mt][1], kf[tn][1], S[mt][tn], 0, 0, 0);
            }

        // max-free softmax: P = exp2(S); packed -> wave-private LDS strip
        #pragma unroll
        for (int mt = 0; mt < 2; ++mt)
            #pragma unroll
            for (int r = 0; r < 4; ++r) {
                float e0 = EXP2F(S[mt][0][r]);
                float e1 = EXP2F(S[mt][1][r]);
                float e2 = EXP2F(S[mt][2][r]);
                float e3 = EXP2F(S[mt][3][r]);
                lsum[mt][r] += (e0 + e1) + (e2 + e3);
                uint2 pk;
                pk.x = (unsigned int)f2bf(e0) | ((unsigned int)f2bf(e1) << 16);
                pk.y = (unsigned int)f2bf(e2) | ((unsigned int)f2bf(e3) << 16);
                int row = 32 * w + 16 * mt + quad * 4 + r;
                *(uint2*)&Plds[row * 64 + (((l15 >> 1) ^ (row & 7)) << 3)
                               + ((l15 & 1) << 2)] = pk;
            }

        // O += P V (wave-private strip: lgkmcnt only)
        bf16x8 pf[2][2];
        #pragma unroll
        for (int mt = 0; mt < 2; ++mt) {
            pf[mt][0] = *(const bf16x8*)&Plds[(32 * w + 16 * mt) * 64 + koff0];
            pf[mt][1] = *(const bf16x8*)&Plds[(32 * w + 16 * mt) * 64 + koff1];
        }
        #pragma unroll
        for (int mt = 0; mt < 2; ++mt)
            #pragma unroll
            for (int tn = 0; tn < 4; ++tn) {
                O[mt][tn] = __builtin_amdgcn_mfma_f32_16x16x32_bf16(
                    pf[mt][0], vf[tn][0], O[mt][tn], 0, 0, 0);
                O[mt][tn] = __builtin_amdgcn_mfma_f32_16x16x32_bf16(
                    pf[mt][1], vf[tn][1], O[mt][tn], 0, 0, 0);
            }

        __syncthreads();   // all waves done with Klds[buf]; next stage visible
        buf ^= 1;
    }

    // epilogue: reduce l over 16 col-lanes; write unnormalized O + l partials
    #pragma unroll
    for (int mt = 0; mt < 2; ++mt)
        #pragma unroll
        for (int r = 0; r < 4; ++r) {
            float l = lsum[mt][r];
            l += __shfl_xor(l, 1);
            l += __shfl_xor(l, 2);
            l += __shfl_xor(l, 4);
            l += __shfl_xor(l, 8);
            int n = q0 + 32 * w + 16 * mt + quad * 4 + r;
            if (l15 == 0) lp[n] = l;
            #pragma unroll
            for (int tn = 0; tn < 4; ++tn)
                op[(size_t)n * DIM + h * HDIM + l15 + 16 * tn] =
                    f2bf(O[mt][tn][r]);
        }
}

// ---------------------------------------------------------------------------
// Merge k-split partials: op0 <- bf16((op0 + op1) / (l0 + l1))  in place.
// ---------------------------------------------------------------------------
__global__ __launch_bounds__(256) void reduce_kernel(
    unsigned short* __restrict__ op0, const unsigned short* __restrict__ op1,
    const float* __restrict__ l0, const float* __restrict__ l1)
{
    int gid = blockIdx.x * 256 + threadIdx.x;   // over N*DIM/4
    int n  = gid >> 7;
    int c4 = gid & 127;
    int h  = c4 >> 4;
    float inv = 1.0f / (l0[h * NPTS + n] + l1[h * NPTS + n]);
    ushort4 a = *(const ushort4*)&op0[(size_t)gid * 4];
    ushort4 b = *(const ushort4*)&op1[(size_t)gid * 4];
    ushort4 o;
    o.x = f2bf((bf2f(a.x) + bf2f(b.x)) * inv);
    o.y = f2bf((bf2f(a.y) + bf2f(b.y)) * inv);
    o.z = f2bf((bf2f(a.z) + bf2f(b.z)) * inv);
    o.w = f2bf((bf2f(a.w) + bf2f(b.w)) * inv);
    *(ushort4*)&op0[(size_t)gid * 4] = o;
}

// ---------------------------------------------------------------------------
// Output projection, bf16 MFMA, direct-global frags (R4, kept).
// ---------------------------------------------------------------------------
__global__ __launch_bounds__(256) void out_mfma_kernel(
    const unsigned short* __restrict__ cc,    // [N][512] bf16 normalized heads
    const unsigned short* __restrict__ wot,   // [512][512] bf16 [e_out][k]
    const float* __restrict__ bo, const float* __restrict__ x,
    float* __restrict__ outp)
{
    const int t = threadIdx.x, w = t >> 6, lane = t & 63;
    const int l15 = lane & 15, quad = lane >> 4;
    const int r0 = blockIdx.x * 128 + w * 32;
    const int c0 = blockIdx.y * 64;

    f32x4 O[2][4];
    #pragma unroll
    for (int mt = 0; mt < 2; ++mt)
        #pragma unroll
        for (int tn = 0; tn < 4; ++tn) O[mt][tn] = (f32x4){0.f, 0.f, 0.f, 0.f};

    for (int k0 = 0; k0 < DIM; k0 += 64) {
        bf16x8 af[2][2], bf[4][2];
        #pragma unroll
        for (int mt = 0; mt < 2; ++mt)
            #pragma unroll
            for (int kc = 0; kc < 2; ++kc)
                af[mt][kc] = *(const bf16x8*)
                    &cc[(size_t)(r0 + 16 * mt + l15) * DIM + k0 + quad * 8 + 32 * kc];
        #pragma unroll
        for (int tn = 0; tn < 4; ++tn)
            #pragma unroll
            for (int kc = 0; kc < 2; ++kc)
                bf[tn][kc] = *(const bf16x8*)
                    &wot[(size_t)(c0 + l15 + 16 * tn) * DIM + k0 + quad * 8 + 32 * kc];
        #pragma unroll
        for (int mt = 0; mt < 2; ++mt)
            #pragma unroll
            for (int tn = 0; tn < 4; ++tn) {
                O[mt][tn] = __builtin_amdgcn_mfma_f32_16x16x32_bf16(
                    af[mt][0], bf[tn][0], O[mt][tn], 0, 0, 0);
                O[mt][tn] = __builtin_amdgcn_mfma_f32_16x16x32_bf16(
                    af[mt][1], bf[tn][1], O[mt][tn], 0, 0, 0);
            }
    }

    #pragma unroll
    for (int mt = 0; mt < 2; ++mt)
        #pragma unroll
        for (int tn = 0; tn < 4; ++tn) {
            int e = c0 + l15 + 16 * tn;
            float be = bo[e];
            #pragma unroll
            for (int r = 0; r < 4; ++r) {
                int n = r0 + 16 * mt + quad * 4 + r;
                outp[(size_t)n * DIM + e] = O[mt][tn][r] + be + x[(size_t)n * DIM + e];
            }
        }
}

extern "C" void kernel_launch(void* const* d_in, const int* in_sizes, int n_in,
                              void* d_out, int out_size, void* d_ws, size_t ws_size,
                              hipStream_t stream) {
    const float* x  = (const float*)d_in[0];
    const float* Wq = (const float*)d_in[1];
    const float* bq = (const float*)d_in[2];
    const float* Wk = (const float*)d_in[3];
    const float* bk = (const float*)d_in[4];
    const float* Wv = (const float*)d_in[5];
    const float* bv = (const float*)d_in[6];
    const float* Wo = (const float*)d_in[7];
    const float* bo = (const float*)d_in[8];
    float* out = (float*)d_out;

    const size_t per = (size_t)NHEAD * NPTS * HDIM;            // 4M elems
    unsigned short* xbf   = (unsigned short*)d_ws;             //  8 MB
    unsigned short* wtq   = xbf + (size_t)NPTS * DIM;          //  1.5 MB
    unsigned short* wot   = wtq + (size_t)24 * HDIM * DIM;     //  0.5 MB
    unsigned short* q_bf  = wot + (size_t)DIM * DIM;           //  8 MB
    unsigned short* k_bf  = q_bf + per;                        //  8 MB
    unsigned short* vt_bf = k_bf + per;                        //  8 MB
    unsigned short* op0   = vt_bf + per;                       //  8 MB
    unsigned short* op1   = op0 + (size_t)NPTS * DIM;          //  8 MB
    float*          lpart = (float*)(op1 + (size_t)NPTS * DIM); // 512 KB
    // total ws: ~50.5 MB

    cvt_x_kernel<<<dim3(NPTS * DIM / 8 / 256), 256, 0, stream>>>(x, xbf);
    tr_w_kernel<<<dim3(8, 1, 24), 256, 0, stream>>>(Wq, Wk, Wv, wtq);
    tr_wo_kernel<<<dim3(8, 8), 256, 0, stream>>>(Wo, wot);
    qkv_mfma_kernel<<<dim3(NPTS / 128, 24), 256, 0, stream>>>(
        xbf, wtq, bq, bk, bv, q_bf, k_bf, vt_bf);
    attn_kernel<<<dim3(NPTS / 128, NHEAD, 2), 256, 0, stream>>>(
        q_bf, k_bf, vt_bf, op0, lpart);
    reduce_kernel<<<dim3(NPTS * DIM / 4 / 256), 256, 0, stream>>>(
        op0, op1, lpart, lpart + (size_t)NHEAD * NPTS);
    out_mfma_kernel<<<dim3(NPTS / 128, DIM / 64), 256, 0, stream>>>(
        op0, wot, bo, x, out);
}

// Round 6
// 458.638 us; speedup vs baseline: 1.3930x; 1.2273x over previous
//
#include <hip/hip_runtime.h>
#include <hip/hip_bf16.h>

#define NPTS 8192
#define DIM  512
#define NHEAD 8
#define HDIM 64

typedef short bf16x8 __attribute__((ext_vector_type(8)));   // 8 bf16 = 4 VGPRs
typedef float f32x4  __attribute__((ext_vector_type(4)));   // MFMA C/D

#define GLOBAL_AS __attribute__((address_space(1)))
#define LDS_AS    __attribute__((address_space(3)))

#if __has_builtin(__builtin_amdgcn_exp2f)
#define EXP2F(x) __builtin_amdgcn_exp2f(x)
#else
#define EXP2F(x) __expf((x) * 0.6931471805599453f)
#endif

// fp32 -> bf16 round-nearest-even
__device__ __forceinline__ unsigned short f2bf(float f) {
    union { float f; unsigned int u; } v; v.f = f;
    unsigned int r = v.u + 0x7FFFu + ((v.u >> 16) & 1u);
    return (unsigned short)(r >> 16);
}
__device__ __forceinline__ float bf2f(unsigned short u) {
    union { unsigned int i; float f; } v; v.i = ((unsigned int)u) << 16;
    return v.f;
}

// ---------------------------------------------------------------------------
// Prep 1: x fp32 -> bf16
// ---------------------------------------------------------------------------
__global__ __launch_bounds__(256) void cvt_x_kernel(
    const float* __restrict__ in, unsigned short* __restrict__ outp)
{
    int gid = blockIdx.x * 256 + threadIdx.x;   // over N*DIM/8
    float4 a = ((const float4*)in)[gid * 2];
    float4 b = ((const float4*)in)[gid * 2 + 1];
    ushort4 ua, ub;
    ua.x = f2bf(a.x); ua.y = f2bf(a.y); ua.z = f2bf(a.z); ua.w = f2bf(a.w);
    ub.x = f2bf(b.x); ub.y = f2bf(b.y); ub.z = f2bf(b.z); ub.w = f2bf(b.w);
    ((ushort4*)outp)[gid * 2]     = ua;
    ((ushort4*)outp)[gid * 2 + 1] = ub;
}

// ---------------------------------------------------------------------------
// Prep 2: Wq/Wk/Wv [h][512][64] fp32 -> wtq [zh][64][512] bf16 (transposed)
// ---------------------------------------------------------------------------
__global__ __launch_bounds__(256) void tr_w_kernel(
    const float* __restrict__ Wq, const float* __restrict__ Wk,
    const float* __restrict__ Wv, unsigned short* __restrict__ wtq)
{
    int zh = blockIdx.z, z = zh >> 3, h = zh & 7;
    const float* src = (z == 0 ? Wq : z == 1 ? Wk : Wv) + (size_t)h * DIM * HDIM;
    unsigned short* dst = wtq + (size_t)zh * HDIM * DIM;
    int k0 = blockIdx.x * 64;
    __shared__ float tile[64][65];
    int t = threadIdx.x, c = t & 63, r = t >> 6;
    #pragma unroll
    for (int i = 0; i < 16; ++i)
        tile[r + 4 * i][c] = src[(size_t)(k0 + r + 4 * i) * HDIM + c];
    __syncthreads();
    #pragma unroll
    for (int i = 0; i < 16; ++i)
        dst[(size_t)(r + 4 * i) * DIM + k0 + c] = f2bf(tile[c][r + 4 * i]);
}

// ---------------------------------------------------------------------------
// Prep 3: Wo [512][512] fp32 -> wot [512][512] bf16 transposed ([e_out][k])
// ---------------------------------------------------------------------------
__global__ __launch_bounds__(256) void tr_wo_kernel(
    const float* __restrict__ Wo, unsigned short* __restrict__ wot)
{
    int k0 = blockIdx.x * 64, e0 = blockIdx.y * 64;
    __shared__ float tile[64][65];
    int t = threadIdx.x, c = t & 63, r = t >> 6;
    #pragma unroll
    for (int i = 0; i < 16; ++i)
        tile[r + 4 * i][c] = Wo[(size_t)(k0 + r + 4 * i) * DIM + e0 + c];
    __syncthreads();
    #pragma unroll
    for (int i = 0; i < 16; ++i)
        wot[(size_t)(e0 + r + 4 * i) * DIM + k0 + c] = f2bf(tile[c][r + 4 * i]);
}

// ---------------------------------------------------------------------------
// QKV projection, bf16 MFMA, direct-global frags.
//   z=0: q_bf[h][n][e]  (scale*log2e folded)   z=1: k_bf[h][n][e]
//   z=2: vt_bf[h][e][kappa(n)]  kappa = (n&~63)+4*(n&15)+((n>>4)&3)
// ---------------------------------------------------------------------------
__global__ __launch_bounds__(256) void qkv_mfma_kernel(
    const unsigned short* __restrict__ xbf,   // [N][512] bf16
    const unsigned short* __restrict__ wtq,   // [24][64][512] bf16
    const float* __restrict__ bq, const float* __restrict__ bk,
    const float* __restrict__ bv,
    unsigned short* __restrict__ q_bf, unsigned short* __restrict__ k_bf,
    unsigned short* __restrict__ vt_bf)
{
    const int zh = blockIdx.y, z = zh >> 3, h = zh & 7;
    const unsigned short* W = wtq + (size_t)zh * HDIM * DIM;
    const float* b = (z == 0 ? bq : z == 1 ? bk : bv) + h * HDIM;
    const int t = threadIdx.x, w = t >> 6, lane = t & 63;
    const int l15 = lane & 15, quad = lane >> 4;
    const int r0 = blockIdx.x * 128 + w * 32;

    f32x4 O[2][4];
    #pragma unroll
    for (int mt = 0; mt < 2; ++mt)
        #pragma unroll
        for (int tn = 0; tn < 4; ++tn) O[mt][tn] = (f32x4){0.f, 0.f, 0.f, 0.f};

    for (int k0 = 0; k0 < DIM; k0 += 64) {
        bf16x8 af[2][2], bf[4][2];
        #pragma unroll
        for (int mt = 0; mt < 2; ++mt)
            #pragma unroll
            for (int kc = 0; kc < 2; ++kc)
                af[mt][kc] = *(const bf16x8*)
                    &xbf[(size_t)(r0 + 16 * mt + l15) * DIM + k0 + quad * 8 + 32 * kc];
        #pragma unroll
        for (int tn = 0; tn < 4; ++tn)
            #pragma unroll
            for (int kc = 0; kc < 2; ++kc)
                bf[tn][kc] = *(const bf16x8*)
                    &W[(size_t)(l15 + 16 * tn) * DIM + k0 + quad * 8 + 32 * kc];
        #pragma unroll
        for (int mt = 0; mt < 2; ++mt)
            #pragma unroll
            for (int tn = 0; tn < 4; ++tn) {
                O[mt][tn] = __builtin_amdgcn_mfma_f32_16x16x32_bf16(
                    af[mt][0], bf[tn][0], O[mt][tn], 0, 0, 0);
                O[mt][tn] = __builtin_amdgcn_mfma_f32_16x16x32_bf16(
                    af[mt][1], bf[tn][1], O[mt][tn], 0, 0, 0);
            }
    }

    if (z < 2) {
        unsigned short* outp = (z == 0 ? q_bf : k_bf) + (size_t)h * NPTS * HDIM;
        const float sc = (z == 0) ? 0.18033688011112042f : 1.0f;  // 0.125*log2e | 1
        #pragma unroll
        for (int mt = 0; mt < 2; ++mt)
            #pragma unroll
            for (int tn = 0; tn < 4; ++tn) {
                int e = l15 + 16 * tn;
                float be = b[e];
                #pragma unroll
                for (int r = 0; r < 4; ++r) {
                    int n = r0 + 16 * mt + quad * 4 + r;
                    outp[(size_t)n * HDIM + e] = f2bf((O[mt][tn][r] + be) * sc);
                }
            }
    } else {
        unsigned short* vt = vt_bf + (size_t)h * HDIM * NPTS;
        #pragma unroll
        for (int mt = 0; mt < 2; ++mt)
            #pragma unroll
            for (int tn = 0; tn < 4; ++tn) {
                int e = l15 + 16 * tn;
                float be = b[e];
                #pragma unroll
                for (int r = 0; r < 4; ++r) {
                    int n = r0 + 16 * mt + quad * 4 + r;
                    int kap = (n & ~63) + ((n & 15) << 2) + ((n >> 4) & 3);
                    vt[(size_t)e * NPTS + kap] = f2bf(O[mt][tn][r] + be);
                }
            }
    }
}

// ---------------------------------------------------------------------------
// MFMA flash attention, R6 = R5 minus the VGPR cap (launch_bounds(256) only:
// R5's __launch_bounds__(256,4) forced VGPR=64 -> ~190 MB scratch spills).
// Double-buffered K staging (one barrier/iter, stage issued a body ahead);
// K via global_load_lds w=16 + XOR source swizzle; V frags direct from
// kappa-ordered global; P via wave-private LDS strip; max-free softmax;
// k-split 2 with linear partials merged by reduce_kernel.
// ---------------------------------------------------------------------------
__global__ __launch_bounds__(256) void attn_kernel(
    const unsigned short* __restrict__ qg,   // [H][N][64] bf16, pre-scaled
    const unsigned short* __restrict__ kg,   // [H][N][64] bf16
    const unsigned short* __restrict__ vtg,  // [H][64][N] bf16, kappa-permuted
    unsigned short* __restrict__ opart,      // [2][N][DIM] bf16 unnormalized
    float* __restrict__ lpart)               // [2][H][N] fp32
{
    const int h  = blockIdx.y;
    const int ks = blockIdx.z;
    const int q0 = blockIdx.x * 128;
    const int kbase = ks * (NPTS / 2);
    const unsigned short* Q  = qg  + (size_t)h * NPTS * HDIM;
    const unsigned short* K  = kg  + (size_t)h * NPTS * HDIM;
    const unsigned short* Vt = vtg + (size_t)h * HDIM * NPTS;
    unsigned short* op = opart + (size_t)ks * NPTS * DIM;
    float* lp = lpart + (size_t)(ks * NHEAD + h) * NPTS;

    __shared__ __align__(16) unsigned short Klds[2][64 * 64];  // 2 x 8 KB
    __shared__ __align__(16) unsigned short Plds[128 * 64];    // 16 KB

    const int t    = threadIdx.x;
    const int w    = t >> 6;
    const int lane = t & 63;
    const int l15  = lane & 15;
    const int quad = lane >> 4;

    const int koff0 = l15 * 64 + (quad ^ (l15 & 7)) * 8;
    const int koff1 = koff0 ^ 32;

    const int srow   = lane >> 3;
    const int schunk = (lane & 7) ^ srow;

    // Q A-frags: rows q0 + 32w + 16mt + l15
    bf16x8 qf[2][2];
    #pragma unroll
    for (int mt = 0; mt < 2; ++mt)
        #pragma unroll
        for (int kc = 0; kc < 2; ++kc)
            qf[mt][kc] = *(const bf16x8*)
                &Q[(size_t)(q0 + 32 * w + 16 * mt + l15) * HDIM + quad * 8 + 32 * kc];

    f32x4 O[2][4];
    float lsum[2][4];
    #pragma unroll
    for (int mt = 0; mt < 2; ++mt) {
        #pragma unroll
        for (int tn = 0; tn < 4; ++tn) O[mt][tn] = (f32x4){0.f, 0.f, 0.f, 0.f};
        #pragma unroll
        for (int r = 0; r < 4; ++r) lsum[mt][r] = 0.f;
    }

    // stage one 64-key tile into Klds[buf]; 4 waves x 2 issues x 16B/lane
    auto stage = [&](int kt, int buf) {
        #pragma unroll
        for (int i = 0; i < 2; ++i) {
            int rb = 16 * w + 8 * i;
            __builtin_amdgcn_global_load_lds(
                (const GLOBAL_AS void*)&K[(size_t)(kbase + kt + rb + srow) * HDIM
                                          + schunk * 8],
                (LDS_AS void*)&Klds[buf][rb * 64], 16, 0, 0);
        }
    };

    stage(0, 0);
    __syncthreads();
    int buf = 0;

    for (int kt = 0; kt < NPTS / 2; kt += 64) {
        // issue next stage first: latency hidden behind this body's compute
        if (kt + 64 < NPTS / 2) stage(kt + 64, buf ^ 1);

        // V frags for this tile (global, consumed after softmax)
        bf16x8 vf[4][2];
        #pragma unroll
        for (int tn = 0; tn < 4; ++tn)
            #pragma unroll
            for (int kc = 0; kc < 2; ++kc)
                vf[tn][kc] = *(const bf16x8*)
                    &Vt[(size_t)(16 * tn + l15) * NPTS + kbase + kt + quad * 8 + 32 * kc];

        // K frags from LDS
        bf16x8 kf[4][2];
        #pragma unroll
        for (int tn = 0; tn < 4; ++tn) {
            kf[tn][0] = *(const bf16x8*)&Klds[buf][1024 * tn + koff0];
            kf[tn][1] = *(const bf16x8*)&Klds[buf][1024 * tn + koff1];
        }

        // S = Q K^T
        f32x4 S[2][4];
        #pragma unroll
        for (int mt = 0; mt < 2; ++mt)
            #pragma unroll
            for (int tn = 0; tn < 4; ++tn) S[mt][tn] = (f32x4){0.f, 0.f, 0.f, 0.f};
        #pragma unroll
        for (int mt = 0; mt < 2; ++mt)
            #pragma unroll
            for (int tn = 0; tn < 4; ++tn) {
                S[mt][tn] = __builtin_amdgcn_mfma_f32_16x16x32_bf16(
                    qf[mt][0], kf[tn][0], S[mt][tn], 0, 0, 0);
                S[mt][tn] = __builtin_amdgcn_mfma_f32_16x16x32_bf16(
                    qf[mt][1], kf[tn][1], S[mt][tn], 0, 0, 0);
            }

        // max-free softmax: P = exp2(S); packed -> wave-private LDS strip
        #pragma unroll
        for (int mt = 0; mt < 2; ++mt)
            #pragma unroll
            for (int r = 0; r < 4; ++r) {
                float e0 = EXP2F(S[mt][0][r]);
                float e1 = EXP2F(S[mt][1][r]);
                float e2 = EXP2F(S[mt][2][r]);
                float e3 = EXP2F(S[mt][3][r]);
                lsum[mt][r] += (e0 + e1) + (e2 + e3);
                uint2 pk;
                pk.x = (unsigned int)f2bf(e0) | ((unsigned int)f2bf(e1) << 16);
                pk.y = (unsigned int)f2bf(e2) | ((unsigned int)f2bf(e3) << 16);
                int row = 32 * w + 16 * mt + quad * 4 + r;
                *(uint2*)&Plds[row * 64 + (((l15 >> 1) ^ (row & 7)) << 3)
                               + ((l15 & 1) << 2)] = pk;
            }

        // O += P V (wave-private strip: lgkmcnt only)
        bf16x8 pf[2][2];
        #pragma unroll
        for (int mt = 0; mt < 2; ++mt) {
            pf[mt][0] = *(const bf16x8*)&Plds[(32 * w + 16 * mt) * 64 + koff0];
            pf[mt][1] = *(const bf16x8*)&Plds[(32 * w + 16 * mt) * 64 + koff1];
        }
        #pragma unroll
        for (int mt = 0; mt < 2; ++mt)
            #pragma unroll
            for (int tn = 0; tn < 4; ++tn) {
                O[mt][tn] = __builtin_amdgcn_mfma_f32_16x16x32_bf16(
                    pf[mt][0], vf[tn][0], O[mt][tn], 0, 0, 0);
                O[mt][tn] = __builtin_amdgcn_mfma_f32_16x16x32_bf16(
                    pf[mt][1], vf[tn][1], O[mt][tn], 0, 0, 0);
            }

        __syncthreads();   // all waves done with Klds[buf]; next stage visible
        buf ^= 1;
    }

    // epilogue: reduce l over 16 col-lanes; write unnormalized O + l partials
    #pragma unroll
    for (int mt = 0; mt < 2; ++mt)
        #pragma unroll
        for (int r = 0; r < 4; ++r) {
            float l = lsum[mt][r];
            l += __shfl_xor(l, 1);
            l += __shfl_xor(l, 2);
            l += __shfl_xor(l, 4);
            l += __shfl_xor(l, 8);
            int n = q0 + 32 * w + 16 * mt + quad * 4 + r;
            if (l15 == 0) lp[n] = l;
            #pragma unroll
            for (int tn = 0; tn < 4; ++tn)
                op[(size_t)n * DIM + h * HDIM + l15 + 16 * tn] =
                    f2bf(O[mt][tn][r]);
        }
}

// ---------------------------------------------------------------------------
// Merge k-split partials: op0 <- bf16((op0 + op1) / (l0 + l1))  in place.
// ---------------------------------------------------------------------------
__global__ __launch_bounds__(256) void reduce_kernel(
    unsigned short* __restrict__ op0, const unsigned short* __restrict__ op1,
    const float* __restrict__ l0, const float* __restrict__ l1)
{
    int gid = blockIdx.x * 256 + threadIdx.x;   // over N*DIM/4
    int n  = gid >> 7;
    int c4 = gid & 127;
    int h  = c4 >> 4;
    float inv = 1.0f / (l0[h * NPTS + n] + l1[h * NPTS + n]);
    ushort4 a = *(const ushort4*)&op0[(size_t)gid * 4];
    ushort4 b = *(const ushort4*)&op1[(size_t)gid * 4];
    ushort4 o;
    o.x = f2bf((bf2f(a.x) + bf2f(b.x)) * inv);
    o.y = f2bf((bf2f(a.y) + bf2f(b.y)) * inv);
    o.z = f2bf((bf2f(a.z) + bf2f(b.z)) * inv);
    o.w = f2bf((bf2f(a.w) + bf2f(b.w)) * inv);
    *(ushort4*)&op0[(size_t)gid * 4] = o;
}

// ---------------------------------------------------------------------------
// Output projection, bf16 MFMA, direct-global frags.
// ---------------------------------------------------------------------------
__global__ __launch_bounds__(256) void out_mfma_kernel(
    const unsigned short* __restrict__ cc,    // [N][512] bf16 normalized heads
    const unsigned short* __restrict__ wot,   // [512][512] bf16 [e_out][k]
    const float* __restrict__ bo, const float* __restrict__ x,
    float* __restrict__ outp)
{
    const int t = threadIdx.x, w = t >> 6, lane = t & 63;
    const int l15 = lane & 15, quad = lane >> 4;
    const int r0 = blockIdx.x * 128 + w * 32;
    const int c0 = blockIdx.y * 64;

    f32x4 O[2][4];
    #pragma unroll
    for (int mt = 0; mt < 2; ++mt)
        #pragma unroll
        for (int tn = 0; tn < 4; ++tn) O[mt][tn] = (f32x4){0.f, 0.f, 0.f, 0.f};

    for (int k0 = 0; k0 < DIM; k0 += 64) {
        bf16x8 af[2][2], bf[4][2];
        #pragma unroll
        for (int mt = 0; mt < 2; ++mt)
            #pragma unroll
            for (int kc = 0; kc < 2; ++kc)
                af[mt][kc] = *(const bf16x8*)
                    &cc[(size_t)(r0 + 16 * mt + l15) * DIM + k0 + quad * 8 + 32 * kc];
        #pragma unroll
        for (int tn = 0; tn < 4; ++tn)
            #pragma unroll
            for (int kc = 0; kc < 2; ++kc)
                bf[tn][kc] = *(const bf16x8*)
                    &wot[(size_t)(c0 + l15 + 16 * tn) * DIM + k0 + quad * 8 + 32 * kc];
        #pragma unroll
        for (int mt = 0; mt < 2; ++mt)
            #pragma unroll
            for (int tn = 0; tn < 4; ++tn) {
                O[mt][tn] = __builtin_amdgcn_mfma_f32_16x16x32_bf16(
                    af[mt][0], bf[tn][0], O[mt][tn], 0, 0, 0);
                O[mt][tn] = __builtin_amdgcn_mfma_f32_16x16x32_bf16(
                    af[mt][1], bf[tn][1], O[mt][tn], 0, 0, 0);
            }
    }

    #pragma unroll
    for (int mt = 0; mt < 2; ++mt)
        #pragma unroll
        for (int tn = 0; tn < 4; ++tn) {
            int e = c0 + l15 + 16 * tn;
            float be = bo[e];
            #pragma unroll
            for (int r = 0; r < 4; ++r) {
                int n = r0 + 16 * mt + quad * 4 + r;
                outp[(size_t)n * DIM + e] = O[mt][tn][r] + be + x[(size_t)n * DIM + e];
            }
        }
}

extern "C" void kernel_launch(void* const* d_in, const int* in_sizes, int n_in,
                              void* d_out, int out_size, void* d_ws, size_t ws_size,
                              hipStream_t stream) {
    const float* x  = (const float*)d_in[0];
    const float* Wq = (const float*)d_in[1];
    const float* bq = (const float*)d_in[2];
    const float* Wk = (const float*)d_in[3];
    const float* bk = (const float*)d_in[4];
    const float* Wv = (const float*)d_in[5];
    const float* bv = (const float*)d_in[6];
    const float* Wo = (const float*)d_in[7];
    const float* bo = (const float*)d_in[8];
    float* out = (float*)d_out;

    const size_t per = (size_t)NHEAD * NPTS * HDIM;            // 4M elems
    unsigned short* xbf   = (unsigned short*)d_ws;             //  8 MB
    unsigned short* wtq   = xbf + (size_t)NPTS * DIM;          //  1.5 MB
    unsigned short* wot   = wtq + (size_t)24 * HDIM * DIM;     //  0.5 MB
    unsigned short* q_bf  = wot + (size_t)DIM * DIM;           //  8 MB
    unsigned short* k_bf  = q_bf + per;                        //  8 MB
    unsigned short* vt_bf = k_bf + per;                        //  8 MB
    unsigned short* op0   = vt_bf + per;                       //  8 MB
    unsigned short* op1   = op0 + (size_t)NPTS * DIM;          //  8 MB
    float*          lpart = (float*)(op1 + (size_t)NPTS * DIM); // 512 KB
    // total ws: ~50.5 MB

    cvt_x_kernel<<<dim3(NPTS * DIM / 8 / 256), 256, 0, stream>>>(x, xbf);
    tr_w_kernel<<<dim3(8, 1, 24), 256, 0, stream>>>(Wq, Wk, Wv, wtq);
    tr_wo_kernel<<<dim3(8, 8), 256, 0, stream>>>(Wo, wot);
    qkv_mfma_kernel<<<dim3(NPTS / 128, 24), 256, 0, stream>>>(
        xbf, wtq, bq, bk, bv, q_bf, k_bf, vt_bf);
    attn_kernel<<<dim3(NPTS / 128, NHEAD, 2), 256, 0, stream>>>(
        q_bf, k_bf, vt_bf, op0, lpart);
    reduce_kernel<<<dim3(NPTS * DIM / 4 / 256), 256, 0, stream>>>(
        op0, op1, lpart, lpart + (size_t)NHEAD * NPTS);
    out_mfma_kernel<<<dim3(NPTS / 128, DIM / 64), 256, 0, stream>>>(
        op0, wot, bo, x, out);
}